// Round 13
// baseline (334.166 us; speedup 1.0000x reference)
//
#include <hip/hip_runtime.h>
#include <hip/hip_bf16.h>

// V=50000, D=512, H=512, L=4, E=40000
#define NV 50000
#define VP2 50176          // 196*256, padded target count (M of the big GEMM)
#define ND 512
#define NH 512
#define NL 4
#define NE 40000
#define CAP 16             // per-(target,layer) list capacity; deg ~ Poisson(0.8)
#define KTOT 2048          // NL*ND concatenated K
#define NKT 32             // K-tiles of 64
#define NWG2 392           // (VP2/256) * (512/256) blocks; 392 = 8*49

typedef short bf16x8 __attribute__((ext_vector_type(8)));  // MFMA A/B frag
typedef float f32x4  __attribute__((ext_vector_type(4)));  // MFMA C/D frag

__device__ __forceinline__ unsigned short f2bf(float f) {
    unsigned int u = __float_as_uint(f);
    u += 0x7FFFu + ((u >> 16) & 1u);
    return (unsigned short)(u >> 16);
}
__device__ __forceinline__ unsigned pack_bf2(float x, float y) {
    return (unsigned)f2bf(x) | ((unsigned)f2bf(y) << 16);
}

// async global->LDS, 16B per lane; LDS dest is wave-uniform base + lane*16
#define GLL16(gp, lp) __builtin_amdgcn_global_load_lds( \
    (const __attribute__((address_space(1))) void*)(gp), \
    (__attribute__((address_space(3))) void*)(lp), 16, 0, 0)

// ---------------------------------------------------------------------------
// Wt2[h][l*512+k] = bf16(W[l][k][h])   (2 MiB at ws+0) — B^T, K-concat layout
// ---------------------------------------------------------------------------
__global__ void wt2_kernel(const float* __restrict__ W, unsigned short* __restrict__ Wt2) {
    int idx = blockIdx.x * 256 + threadIdx.x;     // NL*ND*NH = 4194304
    int l = idx >> 18;
    int r = idx & 262143;
    int k = r >> 9;
    int h = r & 511;
    Wt2[((size_t)h << 11) + (l << 9) + k] = f2bf(W[idx]);
}

// ---------------------------------------------------------------------------
// Per-(target,layer) edge lists: cell = tgt*NL + l, entry = src
// ---------------------------------------------------------------------------
__global__ void place_kernel(const int* __restrict__ adj, int* __restrict__ cnt,
                             int* __restrict__ list) {
    int i = blockIdx.x * 256 + threadIdx.x;       // NL*NE = 160000 exact
    int2 p = ((const int2*)adj)[i];               // p.x = src, p.y = tgt
    int l = i / NE;
    int cell = p.y * NL + l;
    int pos = atomicAdd(&cnt[cell], 1);
    if (pos < CAP) list[cell * CAP + pos] = p.x;
}

// ---------------------------------------------------------------------------
// Pass 1: one wave per (t,l). agg2[t][l*512 + d] (bf16 as u32 pairs)
//   = sum over in-edges of emb[src][d], f32 accumulate in regs.
// ---------------------------------------------------------------------------
__global__ void __launch_bounds__(256)
agg_pull(const float* __restrict__ emb, const int* __restrict__ cnt,
         const int* __restrict__ list, unsigned* __restrict__ agg2) {
    const int wid  = blockIdx.x * 4 + (threadIdx.x >> 6);   // over VP2*NL
    const int lane = threadIdx.x & 63;
    const int t    = wid >> 2;
    const int l    = wid & 3;
    const int cell = wid;                                    // t*NL + l
    const size_t dst = (size_t)t * 1024 + l * 256 + lane;    // u32 units

    int n = cnt[cell]; if (n > CAP) n = CAP;
    const int* lst = list + cell * CAP;

    float2 s0 = {0.f,0.f}, s1 = {0.f,0.f}, s2 = {0.f,0.f}, s3 = {0.f,0.f};
    int j = 0;
    for (; j + 2 <= n; j += 2) {
        const float2* p0 = (const float2*)(emb + (size_t)lst[j]     * ND) + lane;
        const float2* p1 = (const float2*)(emb + (size_t)lst[j + 1] * ND) + lane;
        float2 a0 = p0[0], a1 = p0[64], a2 = p0[128], a3 = p0[192];
        float2 b0 = p1[0], b1 = p1[64], b2 = p1[128], b3 = p1[192];
        s0.x += a0.x + b0.x; s0.y += a0.y + b0.y;
        s1.x += a1.x + b1.x; s1.y += a1.y + b1.y;
        s2.x += a2.x + b2.x; s2.y += a2.y + b2.y;
        s3.x += a3.x + b3.x; s3.y += a3.y + b3.y;
    }
    if (j < n) {
        const float2* p0 = (const float2*)(emb + (size_t)lst[j] * ND) + lane;
        float2 a0 = p0[0], a1 = p0[64], a2 = p0[128], a3 = p0[192];
        s0.x += a0.x; s0.y += a0.y;  s1.x += a1.x; s1.y += a1.y;
        s2.x += a2.x; s2.y += a2.y;  s3.x += a3.x; s3.y += a3.y;
    }
    agg2[dst]       = pack_bf2(s0.x, s0.y);
    agg2[dst + 64]  = pack_bf2(s1.x, s1.y);
    agg2[dst + 128] = pack_bf2(s2.x, s2.y);
    agg2[dst + 192] = pack_bf2(s3.x, s3.y);
}

// ---------------------------------------------------------------------------
// Stage the A tile (256 rows x 64 k) of K-tile kt into buffer (kt&1).
// 4 GLL16/thread; wave w covers rows [r*64 + w*8 .. +8) per round.
// Pre-swizzled global source slot: LDS[row][s'] = global[row][s' ^ (row&7)].
// (R10-verified pattern, bank conflicts = 0.)
// ---------------------------------------------------------------------------
__device__ __forceinline__ void stage_a(
    int kt, int t0, int wave, int lane,
    const unsigned short* __restrict__ agg2,
    unsigned short* sa0, unsigned short* sa1) {
    const int rowin = lane >> 3;                 // 0..7
    const int slt   = lane & 7;                  // 16B slot within row
    unsigned short* sa = (kt & 1) ? sa1 : sa0;
    const int ko = kt * 64;
#pragma unroll
    for (int r = 0; r < 4; ++r) {
        const int rb  = r * 64 + wave * 8;       // wave-uniform row base
        const int row = rb + rowin;
        const unsigned short* src = agg2
            + (size_t)(t0 + row) * KTOT + ko + ((slt ^ (row & 7)) << 3);
        GLL16(src, sa + rb * 64);
    }
}

// ---------------------------------------------------------------------------
// One K-tile (2-phase, single barrier — R10-verified structure), with B read
// DIRECTLY from L2-resident Wt2 (no LDS round-trip): per-tile wave LDS reads
// drop 24 -> 16 (the LDS pipe was the measured 27% ceiling). B wave-loads are
// fully line-coalesced: 16 rows x 64 B consumed exactly.
// ---------------------------------------------------------------------------
template<bool STG>
__device__ __forceinline__ void tile_step(
    int kt, int t0, int n0, int wave, int lane, int wm, int wn,
    const unsigned short* __restrict__ agg2, const unsigned short* __restrict__ Wt2,
    unsigned short* sa0, unsigned short* sa1,
    f32x4 (&acc)[8][4]) {
    const int laneL = lane & 15, laneH = lane >> 4;
    const int ax = laneL & 7;
    const unsigned short* pa = (kt & 1) ? sa1 : sa0;
    const int ko = kt * 64;

    // ---- issue next-tile A stage first (HBM latency hidden under this tile) ----
    if (STG) stage_a(kt + 1, t0, wave, lane, agg2, sa0, sa1);

    // ---- B frags direct from global (L2-hot, ~200cyc, issued early) ----
    bf16x8 bF[4][2];
#pragma unroll
    for (int ni = 0; ni < 4; ++ni)
#pragma unroll
        for (int ks = 0; ks < 2; ++ks) {
            const int h = n0 + wn * 64 + ni * 16 + laneL;
            bF[ni][ks] = *(const bf16x8*)(Wt2 + (size_t)h * KTOT + ko + ks * 32 + laneH * 8);
        }

    // ---- A frags from swizzled LDS; MFMA rows 0-63 then 64-127 ----
    bf16x8 aF[4][2];
#pragma unroll
    for (int mi = 0; mi < 4; ++mi)
#pragma unroll
        for (int ks = 0; ks < 2; ++ks) {
            const int row = wm * 128 + mi * 16 + laneL;
            aF[mi][ks] = *(const bf16x8*)(pa + row * 64 + (((ks * 4 + laneH) ^ ax) << 3));
        }
#pragma unroll
    for (int mi = 0; mi < 4; ++mi)
#pragma unroll
        for (int ni = 0; ni < 4; ++ni)
#pragma unroll
            for (int ks = 0; ks < 2; ++ks)
                acc[mi][ni] = __builtin_amdgcn_mfma_f32_16x16x32_bf16(aF[mi][ks], bF[ni][ks], acc[mi][ni], 0, 0, 0);
#pragma unroll
    for (int mi = 0; mi < 4; ++mi)
#pragma unroll
        for (int ks = 0; ks < 2; ++ks) {
            const int row = wm * 128 + (mi + 4) * 16 + laneL;
            aF[mi][ks] = *(const bf16x8*)(pa + row * 64 + (((ks * 4 + laneH) ^ ax) << 3));
        }
#pragma unroll
    for (int mi = 0; mi < 4; ++mi)
#pragma unroll
        for (int ni = 0; ni < 4; ++ni)
#pragma unroll
            for (int ks = 0; ks < 2; ++ks)
                acc[mi + 4][ni] = __builtin_amdgcn_mfma_f32_16x16x32_bf16(aF[mi][ks], bF[ni][ks], acc[mi + 4][ni], 0, 0, 0);

    __syncthreads();   // drains A(t+1) stage (full-tile age); publish + reuse-safe
}

// ---------------------------------------------------------------------------
// Pass 2: out = relu(agg2[VP2][2048] x Wt2[512][2048]^T).
// BM=BN=256, BK=64, 512 thr, 8 waves (2M x 4N, 128x64 each), A-only LDS dbuf
// (64 KiB), B direct from L2.
// ---------------------------------------------------------------------------
__global__ void __launch_bounds__(512)
gemm_bg(const unsigned short* __restrict__ agg2,
        const unsigned short* __restrict__ Wt2,
        float* __restrict__ out) {
    __shared__ unsigned short s_a[2][256 * 64];   // 64 KiB total

    // bijective XCD chunk swizzle: 392 = 8*49 exactly
    const int orig = blockIdx.x;
    const int wgid = (orig & 7) * (NWG2 / 8) + (orig >> 3);
    const int mt = wgid >> 1, nt = wgid & 1;
    const int t0 = mt * 256, n0 = nt * 256;

    const int tid  = threadIdx.x;
    const int lane = tid & 63;
    const int wave = tid >> 6;                 // 0..7
    const int wm   = wave >> 2;                // M half (128 rows)
    const int wn   = wave & 3;                 // N quarter (64 cols)
    const int laneL = lane & 15, laneH = lane >> 4;

    f32x4 acc[8][4];
#pragma unroll
    for (int mi = 0; mi < 8; ++mi)
#pragma unroll
        for (int ni = 0; ni < 4; ++ni)
            acc[mi][ni] = (f32x4){0.f, 0.f, 0.f, 0.f};

    unsigned short* sa0 = &s_a[0][0]; unsigned short* sa1 = &s_a[1][0];

    // prologue: stage A tile 0, drain, publish
    stage_a(0, t0, wave, lane, agg2, sa0, sa1);
    __syncthreads();

    for (int kt = 0; kt < NKT - 1; ++kt)
        tile_step<true>(kt, t0, n0, wave, lane, wm, wn, agg2, Wt2, sa0, sa1, acc);
    tile_step<false>(NKT - 1, t0, n0, wave, lane, wm, wn, agg2, Wt2, sa0, sa1, acc);

    // ---- epilogue: ReLU + direct stores (D: col=lane&15, row=(lane>>4)*4+i) ----
#pragma unroll
    for (int mi = 0; mi < 8; ++mi) {
#pragma unroll
        for (int i = 0; i < 4; ++i) {
            int t = t0 + wm * 128 + mi * 16 + laneH * 4 + i;
            if (t < NV) {
#pragma unroll
                for (int ni = 0; ni < 4; ++ni) {
                    int h = n0 + wn * 64 + ni * 16 + laneL;
                    out[(size_t)t * NH + h] = fmaxf(acc[mi][ni][i], 0.f);
                }
            }
        }
    }
}

// ---------------------------------------------------------------------------
// Legacy fallback (R1 pipeline) if workspace is too small.
// ---------------------------------------------------------------------------
__global__ void wt_legacy(const float* __restrict__ W, unsigned short* __restrict__ Wt) {
    int idx = blockIdx.x * 256 + threadIdx.x;
    int l = idx >> 18;
    int r = idx & 262143;
    int k = r >> 9;
    int h = r & 511;
    Wt[(l << 18) + (h << 9) + k] = f2bf(W[idx]);
}
__global__ void __launch_bounds__(256)
legacy_msg(const float* __restrict__ emb, const int* __restrict__ adj,
           const unsigned short* __restrict__ Wt, float* __restrict__ out) {
    __shared__ bf16x8 s_a[32 * 64];
    __shared__ int s_src[32];
    __shared__ int s_tgt[32];
    const int bx = blockIdx.x;
    const int l = bx / (NE / 32);
    const int ebase = (bx % (NE / 32)) * 32;
    const int tid = threadIdx.x, lane = tid & 63, wave = tid >> 6;
    if (tid < 32) {
        int2 p = *(const int2*)(adj + ((size_t)l * NE + ebase + tid) * 2);
        s_src[tid] = p.x; s_tgt[tid] = p.y;
    }
    __syncthreads();
    {
        const int r = tid >> 3, part = tid & 7, k0 = part * 64, rxx = r & 7;
        const float* g = emb + (size_t)s_src[r] * ND + k0;
#pragma unroll
        for (int j = 0; j < 8; ++j) {
            float4 f0 = *(const float4*)(g + j * 8);
            float4 f1 = *(const float4*)(g + j * 8 + 4);
            bf16x8 v;
            v[0]=(short)f2bf(f0.x); v[1]=(short)f2bf(f0.y);
            v[2]=(short)f2bf(f0.z); v[3]=(short)f2bf(f0.w);
            v[4]=(short)f2bf(f1.x); v[5]=(short)f2bf(f1.y);
            v[6]=(short)f2bf(f1.z); v[7]=(short)f2bf(f1.w);
            int slot = (k0 >> 3) + j;
            s_a[r * 64 + (slot ^ rxx)] = v;
        }
    }
    __syncthreads();
    const int c0 = wave * 128, laneL = lane & 15, laneH = lane >> 4, arx = laneL & 7;
    f32x4 acc[2][8];
#pragma unroll
    for (int mf = 0; mf < 2; ++mf)
#pragma unroll
        for (int nf = 0; nf < 8; ++nf) acc[mf][nf] = (f32x4){0.f,0.f,0.f,0.f};
    const bf16x8* wb = (const bf16x8*)(Wt + ((size_t)l << 18));
#pragma unroll
    for (int kc = 0; kc < 16; ++kc) {
        int slot = kc * 4 + laneH;
        bf16x8 a0 = s_a[laneL * 64 + (slot ^ arx)];
        bf16x8 a1 = s_a[(16 + laneL) * 64 + (slot ^ arx)];
#pragma unroll
        for (int nf = 0; nf < 8; ++nf) {
            bf16x8 b = wb[(c0 + nf * 16 + laneL) * 64 + slot];
            acc[0][nf] = __builtin_amdgcn_mfma_f32_16x16x32_bf16(a0, b, acc[0][nf], 0, 0, 0);
            acc[1][nf] = __builtin_amdgcn_mfma_f32_16x16x32_bf16(a1, b, acc[1][nf], 0, 0, 0);
        }
    }
#pragma unroll
    for (int mf = 0; mf < 2; ++mf)
#pragma unroll
        for (int nf = 0; nf < 8; ++nf) {
            int h = c0 + nf * 16 + laneL;
#pragma unroll
            for (int i = 0; i < 4; ++i) {
                int er = mf * 16 + laneH * 4 + i;
                atomicAdd(out + (size_t)s_tgt[er] * NH + h, acc[mf][nf][i]);
            }
        }
}
__global__ void legacy_relu(float* __restrict__ o, int n4) {
    int stride = gridDim.x * blockDim.x;
    for (int i = blockIdx.x * blockDim.x + threadIdx.x; i < n4; i += stride) {
        float4 v = ((float4*)o)[i];
        v.x = fmaxf(v.x, 0.f); v.y = fmaxf(v.y, 0.f);
        v.z = fmaxf(v.z, 0.f); v.w = fmaxf(v.w, 0.f);
        ((float4*)o)[i] = v;
    }
}

extern "C" void kernel_launch(void* const* d_in, const int* in_sizes, int n_in,
                              void* d_out, int out_size, void* d_ws, size_t ws_size,
                              hipStream_t stream) {
    const float* emb = (const float*)d_in[0];   // [V, D] f32
    const int*   adj = (const int*)d_in[1];     // [L, E, 2] i32
    const float* W   = (const float*)d_in[2];   // [L, D, H] f32
    float* out = (float*)d_out;                 // [V, H] f32
    char* ws = (char*)d_ws;

    unsigned short* Wt2  = (unsigned short*)ws;                 // @0,    2 MiB
    int*            cnt  = (int*)(ws + 2621440);                // @2.5M, 802,816 B
    int*            list = (int*)(ws + 3670016);                // @3.5M, 12.25 MiB
    unsigned short* agg2 = (unsigned short*)(ws + (16u << 20)); // @16M,  196 MiB

    const size_t need = (16u << 20) + (size_t)VP2 * KTOT * 2;   // ~212 MiB

    if (ws_size >= need) {
        hipMemsetAsync(cnt, 0, (size_t)VP2 * NL * sizeof(int), stream);
        wt2_kernel<<<(NL * ND * NH) / 256, 256, 0, stream>>>(W, Wt2);
        place_kernel<<<(NL * NE) / 256, 256, 0, stream>>>(adj, cnt, list);
        agg_pull<<<(VP2 * NL) / 4, 256, 0, stream>>>(emb, cnt, list, (unsigned*)agg2);
        gemm_bg<<<NWG2, 512, 0, stream>>>(agg2, Wt2, out);
    } else {
        // legacy scatter path (R1)
        hipMemsetAsync(d_out, 0, (size_t)out_size * sizeof(float), stream);
        wt_legacy<<<(NL * ND * NH) / 256, 256, 0, stream>>>(W, Wt2);
        legacy_msg<<<NL * (NE / 32), 256, 0, stream>>>(emb, adj, Wt2, out);
        legacy_relu<<<2048, 256, 0, stream>>>(out, out_size / 4);
    }
}

// Round 14
// 321.379 us; speedup vs baseline: 1.0398x; 1.0398x over previous
//
#include <hip/hip_runtime.h>
#include <hip/hip_bf16.h>

// V=50000, D=512, H=512, L=4, E=40000
#define NV 50000
#define VP2 50176          // 196*256, padded target count (M of the big GEMM)
#define ND 512
#define NH 512
#define NL 4
#define NE 40000
#define CAP 16             // per-(target,layer) list capacity; deg ~ Poisson(0.8)
#define KTOT 2048          // NL*ND concatenated K
#define NKT 64             // K-tiles of 32
#define NWG4 784           // (VP2/256) * (512/128); 784 = 8*98 exact

typedef short bf16x8 __attribute__((ext_vector_type(8)));  // MFMA A/B frag
typedef float f32x4  __attribute__((ext_vector_type(4)));  // MFMA C/D frag

__device__ __forceinline__ unsigned short f2bf(float f) {
    unsigned int u = __float_as_uint(f);
    u += 0x7FFFu + ((u >> 16) & 1u);
    return (unsigned short)(u >> 16);
}
__device__ __forceinline__ unsigned pack_bf2(float x, float y) {
    return (unsigned)f2bf(x) | ((unsigned)f2bf(y) << 16);
}

// async global->LDS, 16B per lane; LDS dest is wave-uniform base + lane*16
#define GLL16(gp, lp) __builtin_amdgcn_global_load_lds( \
    (const __attribute__((address_space(1))) void*)(gp), \
    (__attribute__((address_space(3))) void*)(lp), 16, 0, 0)

// ---------------------------------------------------------------------------
// Wt2[h][l*512+k] = bf16(W[l][k][h])   (2 MiB at ws+0) — B^T, K-concat layout
// ---------------------------------------------------------------------------
__global__ void wt2_kernel(const float* __restrict__ W, unsigned short* __restrict__ Wt2) {
    int idx = blockIdx.x * 256 + threadIdx.x;     // NL*ND*NH = 4194304
    int l = idx >> 18;
    int r = idx & 262143;
    int k = r >> 9;
    int h = r & 511;
    Wt2[((size_t)h << 11) + (l << 9) + k] = f2bf(W[idx]);
}

// ---------------------------------------------------------------------------
// Per-(target,layer) edge lists: cell = tgt*NL + l, entry = src
// ---------------------------------------------------------------------------
__global__ void place_kernel(const int* __restrict__ adj, int* __restrict__ cnt,
                             int* __restrict__ list) {
    int i = blockIdx.x * 256 + threadIdx.x;       // NL*NE = 160000 exact
    int2 p = ((const int2*)adj)[i];               // p.x = src, p.y = tgt
    int l = i / NE;
    int cell = p.y * NL + l;
    int pos = atomicAdd(&cnt[cell], 1);
    if (pos < CAP) list[cell * CAP + pos] = p.x;
}

// ---------------------------------------------------------------------------
// Pass 1: one wave per (t,l). agg2[t][l*512 + d] (bf16 as u32 pairs)
//   = sum over in-edges of emb[src][d], f32 accumulate in regs.
// ---------------------------------------------------------------------------
__global__ void __launch_bounds__(256)
agg_pull(const float* __restrict__ emb, const int* __restrict__ cnt,
         const int* __restrict__ list, unsigned* __restrict__ agg2) {
    const int wid  = blockIdx.x * 4 + (threadIdx.x >> 6);   // over VP2*NL
    const int lane = threadIdx.x & 63;
    const int t    = wid >> 2;
    const int l    = wid & 3;
    const int cell = wid;                                    // t*NL + l
    const size_t dst = (size_t)t * 1024 + l * 256 + lane;    // u32 units

    int n = cnt[cell]; if (n > CAP) n = CAP;
    const int* lst = list + cell * CAP;

    float2 s0 = {0.f,0.f}, s1 = {0.f,0.f}, s2 = {0.f,0.f}, s3 = {0.f,0.f};
    int j = 0;
    for (; j + 2 <= n; j += 2) {
        const float2* p0 = (const float2*)(emb + (size_t)lst[j]     * ND) + lane;
        const float2* p1 = (const float2*)(emb + (size_t)lst[j + 1] * ND) + lane;
        float2 a0 = p0[0], a1 = p0[64], a2 = p0[128], a3 = p0[192];
        float2 b0 = p1[0], b1 = p1[64], b2 = p1[128], b3 = p1[192];
        s0.x += a0.x + b0.x; s0.y += a0.y + b0.y;
        s1.x += a1.x + b1.x; s1.y += a1.y + b1.y;
        s2.x += a2.x + b2.x; s2.y += a2.y + b2.y;
        s3.x += a3.x + b3.x; s3.y += a3.y + b3.y;
    }
    if (j < n) {
        const float2* p0 = (const float2*)(emb + (size_t)lst[j] * ND) + lane;
        float2 a0 = p0[0], a1 = p0[64], a2 = p0[128], a3 = p0[192];
        s0.x += a0.x; s0.y += a0.y;  s1.x += a1.x; s1.y += a1.y;
        s2.x += a2.x; s2.y += a2.y;  s3.x += a3.x; s3.y += a3.y;
    }
    agg2[dst]       = pack_bf2(s0.x, s0.y);
    agg2[dst + 64]  = pack_bf2(s1.x, s1.y);
    agg2[dst + 128] = pack_bf2(s2.x, s2.y);
    agg2[dst + 192] = pack_bf2(s3.x, s3.y);
}

// ---------------------------------------------------------------------------
// Pass 2: out = relu(agg2[VP2][2048] x Wt2[512][2048]^T).
// BM=256, BN=128, BK=32, 512 thr, 8 waves (4M x 2N, 64x64 each).
// LDS 48 KiB dbuf -> 2 blocks/CU (16 waves/CU): co-resident block hides the
// per-tile vmcnt(0)+barrier drain (m114 mechanism; R10's 1-block/CU stall).
// Swizzle: LDS[row][s'] holds global slot s' ^ g(row), g(row)=(row&3)^((row>>2)&3);
// stage source XOR is lane-pure; frag-read banks spread 8x2-way (free, m136).
// ---------------------------------------------------------------------------
__global__ void __launch_bounds__(512, 4)
gemm32(const unsigned short* __restrict__ agg2,
       const unsigned short* __restrict__ Wt2,
       float* __restrict__ out) {
    // units are bf16 (2B). Row = 32 bf16 = 64 B = 4 slots of 16 B.
    __shared__ unsigned short s_a[2 * 256 * 32];   // 32 KiB (2 buf x 16 KiB)
    __shared__ unsigned short s_b[2 * 128 * 32];   // 16 KiB (2 buf x 8 KiB)

    // bijective XCD chunk swizzle: 784 = 8*98 exact; wgid = mt*4 + nt
    const int orig = blockIdx.x;
    const int wgid = (orig & 7) * (NWG4 / 8) + (orig >> 3);
    const int mt = wgid >> 2, nt = wgid & 3;
    const int t0 = mt * 256, n0 = nt * 128;

    const int tid  = threadIdx.x;
    const int lane = tid & 63;
    const int wave = tid >> 6;                 // 0..7
    const int wm   = wave >> 1;                // M quarter (64 rows)
    const int wn   = wave & 1;                 // N half (64 cols)
    const int laneL = lane & 15, laneH = lane >> 4;

    // ---- staging geometry (per 16-row chunk: lane -> row=chunk*16+(lane>>2),
    //      LDS slot = lane&3, global k-slot = slot ^ g(row) = lane-pure) ----
    const int rowin = lane >> 2;                       // 0..15
    const int sx    = (lane & 3) ^ (rowin & 3) ^ ((rowin >> 2) & 3);
    // A: 16 chunks, wave covers chunks {wave*2, wave*2+1}; B: 8 chunks, chunk=wave.
    const unsigned short* srcA0 = agg2 + (size_t)(t0 + (wave * 2 + 0) * 16 + rowin) * KTOT + sx * 8;
    const unsigned short* srcA1 = agg2 + (size_t)(t0 + (wave * 2 + 1) * 16 + rowin) * KTOT + sx * 8;
    const unsigned short* srcB  = Wt2  + (size_t)(n0 + wave * 16 + rowin) * KTOT + sx * 8;
    // LDS dests (linear, wave-uniform base + lane*16B); +parity*buf later
    const int ldsA0 = (wave * 2 + 0) * 512 + lane * 8;   // units
    const int ldsA1 = (wave * 2 + 1) * 512 + lane * 8;
    const int ldsB  = wave * 512 + lane * 8;

    // ---- fragment-read addressing: base + compile-time offsets ----
    const int rx = (laneL & 3) ^ (laneL >> 2);           // g(row) for row=base16+laneL
    const int fa = (wm * 64 + laneL) * 32 + ((laneH ^ rx) << 3);  // A units (mi via +16*32)
    const int fb = (wn * 64 + laneL) * 32 + ((laneH ^ rx) << 3);  // B units

    f32x4 acc[4][4];
#pragma unroll
    for (int mi = 0; mi < 4; ++mi)
#pragma unroll
        for (int ni = 0; ni < 4; ++ni)
            acc[mi][ni] = (f32x4){0.f, 0.f, 0.f, 0.f};

#define STAGE_T(P) do { \
    GLL16(srcA0, s_a + (P) * 8192 + ldsA0); \
    GLL16(srcA1, s_a + (P) * 8192 + ldsA1); \
    GLL16(srcB,  s_b + (P) * 4096 + ldsB);  \
    srcA0 += 32; srcA1 += 32; srcB += 32; } while (0)

#define COMPUTE_T(P) do { \
    const unsigned short* pa = s_a + (P) * 8192; \
    const unsigned short* pb = s_b + (P) * 4096; \
    bf16x8 aF[4], bF[4]; \
    _Pragma("unroll") \
    for (int ni = 0; ni < 4; ++ni) bF[ni] = *(const bf16x8*)(pb + fb + ni * 512); \
    _Pragma("unroll") \
    for (int mi = 0; mi < 4; ++mi) aF[mi] = *(const bf16x8*)(pa + fa + mi * 512); \
    _Pragma("unroll") \
    for (int mi = 0; mi < 4; ++mi) \
        _Pragma("unroll") \
        for (int ni = 0; ni < 4; ++ni) \
            acc[mi][ni] = __builtin_amdgcn_mfma_f32_16x16x32_bf16(aF[mi], bF[ni], acc[mi][ni], 0, 0, 0); \
    } while (0)

    // prologue: stage tile 0 into buf 0
    STAGE_T(0);
    __syncthreads();

    // steady: tiles 0..61 in parity pairs, each stages tile+1
#pragma unroll 1
    for (int it = 0; it < 31; ++it) {
        STAGE_T(1); COMPUTE_T(0); __syncthreads();
        STAGE_T(0); COMPUTE_T(1); __syncthreads();
    }
    // kt=62 stages 63; kt=63 stages nothing
    STAGE_T(1); COMPUTE_T(0); __syncthreads();
    COMPUTE_T(1);

#undef STAGE_T
#undef COMPUTE_T

    // ---- epilogue: ReLU + direct stores (D: col=lane&15, row=(lane>>4)*4+i) ----
#pragma unroll
    for (int mi = 0; mi < 4; ++mi) {
#pragma unroll
        for (int i = 0; i < 4; ++i) {
            int t = t0 + wm * 64 + mi * 16 + laneH * 4 + i;
            if (t < NV) {
#pragma unroll
                for (int ni = 0; ni < 4; ++ni) {
                    int h = n0 + wn * 64 + ni * 16 + laneL;
                    out[(size_t)t * NH + h] = fmaxf(acc[mi][ni][i], 0.f);
                }
            }
        }
    }
}

// ---------------------------------------------------------------------------
// Legacy fallback (R1 pipeline) if workspace is too small.
// ---------------------------------------------------------------------------
__global__ void wt_legacy(const float* __restrict__ W, unsigned short* __restrict__ Wt) {
    int idx = blockIdx.x * 256 + threadIdx.x;
    int l = idx >> 18;
    int r = idx & 262143;
    int k = r >> 9;
    int h = r & 511;
    Wt[(l << 18) + (h << 9) + k] = f2bf(W[idx]);
}
__global__ void __launch_bounds__(256)
legacy_msg(const float* __restrict__ emb, const int* __restrict__ adj,
           const unsigned short* __restrict__ Wt, float* __restrict__ out) {
    __shared__ bf16x8 s_a[32 * 64];
    __shared__ int s_src[32];
    __shared__ int s_tgt[32];
    const int bx = blockIdx.x;
    const int l = bx / (NE / 32);
    const int ebase = (bx % (NE / 32)) * 32;
    const int tid = threadIdx.x, lane = tid & 63, wave = tid >> 6;
    if (tid < 32) {
        int2 p = *(const int2*)(adj + ((size_t)l * NE + ebase + tid) * 2);
        s_src[tid] = p.x; s_tgt[tid] = p.y;
    }
    __syncthreads();
    {
        const int r = tid >> 3, part = tid & 7, k0 = part * 64, rxx = r & 7;
        const float* g = emb + (size_t)s_src[r] * ND + k0;
#pragma unroll
        for (int j = 0; j < 8; ++j) {
            float4 f0 = *(const float4*)(g + j * 8);
            float4 f1 = *(const float4*)(g + j * 8 + 4);
            bf16x8 v;
            v[0]=(short)f2bf(f0.x); v[1]=(short)f2bf(f0.y);
            v[2]=(short)f2bf(f0.z); v[3]=(short)f2bf(f0.w);
            v[4]=(short)f2bf(f1.x); v[5]=(short)f2bf(f1.y);
            v[6]=(short)f2bf(f1.z); v[7]=(short)f2bf(f1.w);
            int slot = (k0 >> 3) + j;
            s_a[r * 64 + (slot ^ rxx)] = v;
        }
    }
    __syncthreads();
    const int c0 = wave * 128, laneL = lane & 15, laneH = lane >> 4, arx = laneL & 7;
    f32x4 acc[2][8];
#pragma unroll
    for (int mf = 0; mf < 2; ++mf)
#pragma unroll
        for (int nf = 0; nf < 8; ++nf) acc[mf][nf] = (f32x4){0.f,0.f,0.f,0.f};
    const bf16x8* wb = (const bf16x8*)(Wt + ((size_t)l << 18));
#pragma unroll
    for (int kc = 0; kc < 16; ++kc) {
        int slot = kc * 4 + laneH;
        bf16x8 a0 = s_a[laneL * 64 + (slot ^ arx)];
        bf16x8 a1 = s_a[(16 + laneL) * 64 + (slot ^ arx)];
#pragma unroll
        for (int nf = 0; nf < 8; ++nf) {
            bf16x8 b = wb[(c0 + nf * 16 + laneL) * 64 + slot];
            acc[0][nf] = __builtin_amdgcn_mfma_f32_16x16x32_bf16(a0, b, acc[0][nf], 0, 0, 0);
            acc[1][nf] = __builtin_amdgcn_mfma_f32_16x16x32_bf16(a1, b, acc[1][nf], 0, 0, 0);
        }
    }
#pragma unroll
    for (int mf = 0; mf < 2; ++mf)
#pragma unroll
        for (int nf = 0; nf < 8; ++nf) {
            int h = c0 + nf * 16 + laneL;
#pragma unroll
            for (int i = 0; i < 4; ++i) {
                int er = mf * 16 + laneH * 4 + i;
                atomicAdd(out + (size_t)s_tgt[er] * NH + h, acc[mf][nf][i]);
            }
        }
}
__global__ void legacy_relu(float* __restrict__ o, int n4) {
    int stride = gridDim.x * blockDim.x;
    for (int i = blockIdx.x * blockDim.x + threadIdx.x; i < n4; i += stride) {
        float4 v = ((float4*)o)[i];
        v.x = fmaxf(v.x, 0.f); v.y = fmaxf(v.y, 0.f);
        v.z = fmaxf(v.z, 0.f); v.w = fmaxf(v.w, 0.f);
        ((float4*)o)[i] = v;
    }
}

extern "C" void kernel_launch(void* const* d_in, const int* in_sizes, int n_in,
                              void* d_out, int out_size, void* d_ws, size_t ws_size,
                              hipStream_t stream) {
    const float* emb = (const float*)d_in[0];   // [V, D] f32
    const int*   adj = (const int*)d_in[1];     // [L, E, 2] i32
    const float* W   = (const float*)d_in[2];   // [L, D, H] f32
    float* out = (float*)d_out;                 // [V, H] f32
    char* ws = (char*)d_ws;

    unsigned short* Wt2  = (unsigned short*)ws;                 // @0,    2 MiB
    int*            cnt  = (int*)(ws + 2621440);                // @2.5M, 802,816 B
    int*            list = (int*)(ws + 3670016);                // @3.5M, 12.25 MiB
    unsigned short* agg2 = (unsigned short*)(ws + (16u << 20)); // @16M,  196 MiB

    const size_t need = (16u << 20) + (size_t)VP2 * KTOT * 2;   // ~212 MiB

    if (ws_size >= need) {
        hipMemsetAsync(cnt, 0, (size_t)VP2 * NL * sizeof(int), stream);
        wt2_kernel<<<(NL * ND * NH) / 256, 256, 0, stream>>>(W, Wt2);
        place_kernel<<<(NL * NE) / 256, 256, 0, stream>>>(adj, cnt, list);
        agg_pull<<<(VP2 * NL) / 4, 256, 0, stream>>>(emb, cnt, list, (unsigned*)agg2);
        gemm32<<<NWG4, 512, 0, stream>>>(agg2, Wt2, out);
    } else {
        // legacy scatter path (R1)
        hipMemsetAsync(d_out, 0, (size_t)out_size * sizeof(float), stream);
        wt_legacy<<<(NL * ND * NH) / 256, 256, 0, stream>>>(W, Wt2);
        legacy_msg<<<NL * (NE / 32), 256, 0, stream>>>(emb, adj, Wt2, out);
        legacy_relu<<<2048, 256, 0, stream>>>(out, out_size / 4);
    }
}